// Round 1
// baseline (822.839 us; speedup 1.0000x reference)
//
#include <hip/hip_runtime.h>

typedef unsigned short u16;
typedef __attribute__((ext_vector_type(8))) short bf16x8;
typedef __attribute__((ext_vector_type(8))) unsigned short u16x8;
typedef __attribute__((ext_vector_type(4))) float f32x4;

__device__ __forceinline__ u16 f2b(float f) {
  unsigned u = __float_as_uint(f);
  u += 0x7fffu + ((u >> 16) & 1u);
  return (u16)(u >> 16);
}

// ---------------- cast fp32 -> bf16 (vectorized) ----------------
__global__ __launch_bounds__(256) void cast_k(const float* __restrict__ s,
                                              u16* __restrict__ d, int n4) {
  int i = blockIdx.x * 256 + threadIdx.x;
  if (i >= n4) return;
  float4 v = *(const float4*)(s + (size_t)i * 4);
  ushort4 o = make_ushort4(f2b(v.x), f2b(v.y), f2b(v.z), f2b(v.w));
  *(ushort4*)(d + (size_t)i * 4) = o;
}

// ---------------- fp32 [R x C] -> bf16 transposed [C x R] ----------------
// grid: (C/32, R/32), block (32,8)
__global__ __launch_bounds__(256) void transpose_k(const float* __restrict__ src,
                                                   u16* __restrict__ dst,
                                                   int ldsrc, int lddst) {
  __shared__ float t[32][33];
  int c0 = blockIdx.x * 32, r0 = blockIdx.y * 32;
  int tx = threadIdx.x, ty = threadIdx.y;
#pragma unroll
  for (int i = 0; i < 4; ++i)
    t[ty + i * 8][tx] = src[(size_t)(r0 + ty + i * 8) * ldsrc + c0 + tx];
  __syncthreads();
#pragma unroll
  for (int i = 0; i < 4; ++i)
    dst[(size_t)(c0 + ty + i * 8) * lddst + r0 + tx] = f2b(t[tx][ty + i * 8]);
}

// ---------------- V head-transpose: qkv[(b*S+s)*3072 + 2048 + h*64 + d] -> vt[bh][d][s]
// grid: (S/32=32, DK/32=2, 64), block (32,8)
__global__ __launch_bounds__(256) void transpose_v_k(const u16* __restrict__ qkv,
                                                     u16* __restrict__ vt) {
  __shared__ u16 t[32][33];
  int z = blockIdx.z;
  int b = z >> 4, h = z & 15;
  int s0 = blockIdx.x * 32, d0 = blockIdx.y * 32;
  int tx = threadIdx.x, ty = threadIdx.y;
  const u16* src = qkv + (size_t)(b * 1024) * 3072 + 2048 + h * 64;
  u16* dst = vt + (size_t)z * 65536;
#pragma unroll
  for (int i = 0; i < 4; ++i)
    t[ty + i * 8][tx] = src[(size_t)(s0 + ty + i * 8) * 3072 + d0 + tx];
  __syncthreads();
#pragma unroll
  for (int i = 0; i < 4; ++i)
    dst[(size_t)(d0 + ty + i * 8) * 1024 + s0 + tx] = t[tx][ty + i * 8];
}

// ---------------- GEMM: C[M,N] = A[M,K] * Bt[N,K]^T (+bias, relu)
// Block 256 thr = 4 waves (2x2), tile 128 x BN, wave 64 x BN/2, MFMA 16x16x32 bf16.
// Batched via blockIdx.z: off = (z/ZD)*Hi + (z%ZD)*Lo  (element offsets).
template <int BN, int AF32, int BIAS, int RELU, int SB16, int SF32>
__global__ __launch_bounds__(256) void gemm_k(
    const u16* __restrict__ Ab, const float* __restrict__ Af,
    long aHi, long aLo, int lda,
    const u16* __restrict__ Bt, long bHi, long bLo, int ldb,
    float* __restrict__ Cf, u16* __restrict__ Cb,
    long cHi, long cLo, int ldc,
    const float* __restrict__ bias, int K, int ZD) {
  constexpr int NT = BN / 32;  // n-tiles per wave
  __shared__ u16 As[128 * 40];
  __shared__ u16 Bs[BN * 40];

  const int tid = threadIdx.x;
  const int lane = tid & 63;
  const int wave = tid >> 6;
  const int waveM = wave >> 1, waveN = wave & 1;
  const int quad = lane >> 4, l16 = lane & 15;

  const int zb = blockIdx.z / ZD, zr = blockIdx.z % ZD;
  const long aOff = zb * aHi + zr * aLo;
  const long bOff = zb * bHi + zr * bLo;
  const long cOff = zb * cHi + zr * cLo;

  const int row0 = blockIdx.y * 128;
  const int col0 = blockIdx.x * BN;

  f32x4 acc[4][NT] = {};

  for (int k0 = 0; k0 < K; k0 += 32) {
    // stage A: 128x32 bf16, 8 elems/thread/iter
#pragma unroll
    for (int it = 0; it < 2; ++it) {
      int e = (it * 256 + tid) * 8;
      int r = e >> 5, c = e & 31;
      if (AF32) {
        const float4* p = (const float4*)(Af + aOff + (long)(row0 + r) * lda + k0 + c);
        float4 v0 = p[0], v1 = p[1];
        u16x8 wv;
        wv[0] = f2b(v0.x); wv[1] = f2b(v0.y); wv[2] = f2b(v0.z); wv[3] = f2b(v0.w);
        wv[4] = f2b(v1.x); wv[5] = f2b(v1.y); wv[6] = f2b(v1.z); wv[7] = f2b(v1.w);
        *(u16x8*)&As[r * 40 + c] = wv;
      } else {
        uint4 v = *(const uint4*)(Ab + aOff + (long)(row0 + r) * lda + k0 + c);
        *(uint4*)&As[r * 40 + c] = v;
      }
    }
    // stage Bt: BN x 32 bf16
#pragma unroll
    for (int it = 0; it < BN / 64; ++it) {
      int e = (it * 256 + tid) * 8;
      int r = e >> 5, c = e & 31;
      uint4 v = *(const uint4*)(Bt + bOff + (long)(col0 + r) * ldb + k0 + c);
      *(uint4*)&Bs[r * 40 + c] = v;
    }
    __syncthreads();

    bf16x8 af[4], bfr[NT];
#pragma unroll
    for (int mi = 0; mi < 4; ++mi)
      af[mi] = *(const bf16x8*)&As[(waveM * 64 + mi * 16 + l16) * 40 + quad * 8];
#pragma unroll
    for (int ni = 0; ni < NT; ++ni)
      bfr[ni] = *(const bf16x8*)&Bs[(waveN * (BN / 2) + ni * 16 + l16) * 40 + quad * 8];
#pragma unroll
    for (int mi = 0; mi < 4; ++mi)
#pragma unroll
      for (int ni = 0; ni < NT; ++ni)
        acc[mi][ni] = __builtin_amdgcn_mfma_f32_16x16x32_bf16(af[mi], bfr[ni], acc[mi][ni], 0, 0, 0);
    __syncthreads();
  }

  // epilogue: D[row=quad*4+r][col=l16] per 16x16 tile
#pragma unroll
  for (int ni = 0; ni < NT; ++ni) {
    int col = col0 + waveN * (BN / 2) + ni * 16 + l16;
    float bv = BIAS ? bias[col] : 0.f;
#pragma unroll
    for (int mi = 0; mi < 4; ++mi) {
#pragma unroll
      for (int r = 0; r < 4; ++r) {
        int row = row0 + waveM * 64 + mi * 16 + quad * 4 + r;
        float v = acc[mi][ni][r] + bv;
        if (RELU) v = fmaxf(v, 0.f);
        long idx = cOff + (long)row * ldc + col;
        if (SF32) Cf[idx] = v;
        if (SB16) Cb[idx] = f2b(v);
      }
    }
  }
}

// ---------------- row softmax, in place, scale 1/8 folded in ----------------
// one block per row of 1024 floats
__global__ __launch_bounds__(256) void softmax_k(float* __restrict__ a) {
  long row = blockIdx.x;
  int tid = threadIdx.x;
  float* p = a + row * 1024 + tid * 4;
  float4 v = *(const float4*)p;
  float m = fmaxf(fmaxf(v.x, v.y), fmaxf(v.z, v.w));
#pragma unroll
  for (int d = 32; d > 0; d >>= 1) m = fmaxf(m, __shfl_xor(m, d));
  __shared__ float red[4];
  if ((tid & 63) == 0) red[tid >> 6] = m;
  __syncthreads();
  m = fmaxf(fmaxf(red[0], red[1]), fmaxf(red[2], red[3]));
  v.x = __expf((v.x - m) * 0.125f);
  v.y = __expf((v.y - m) * 0.125f);
  v.z = __expf((v.z - m) * 0.125f);
  v.w = __expf((v.w - m) * 0.125f);
  float s = v.x + v.y + v.z + v.w;
#pragma unroll
  for (int d = 32; d > 0; d >>= 1) s += __shfl_xor(s, d);
  __shared__ float red2[4];
  if ((tid & 63) == 0) red2[tid >> 6] = s;
  __syncthreads();
  s = red2[0] + red2[1] + red2[2] + red2[3];
  float r = 1.f / s;
  v.x *= r; v.y *= r; v.z *= r; v.w *= r;
  *(float4*)p = v;
}

// ---------------- fused residual add + layernorm, row of 1024 ----------------
template <int WB16>
__global__ __launch_bounds__(256) void add_ln_k(const float* __restrict__ xp,
                                                const float* __restrict__ yp,
                                                const float* __restrict__ g,
                                                const float* __restrict__ bta,
                                                float* __restrict__ of,
                                                u16* __restrict__ ob) {
  long row = blockIdx.x;
  int tid = threadIdx.x;
  const float4 xv = *(const float4*)(xp + row * 1024 + tid * 4);
  const float4 yv = *(const float4*)(yp + row * 1024 + tid * 4);
  float4 v = make_float4(xv.x + yv.x, xv.y + yv.y, xv.z + yv.z, xv.w + yv.w);
  float s1 = v.x + v.y + v.z + v.w;
  float s2 = v.x * v.x + v.y * v.y + v.z * v.z + v.w * v.w;
#pragma unroll
  for (int d = 32; d > 0; d >>= 1) {
    s1 += __shfl_xor(s1, d);
    s2 += __shfl_xor(s2, d);
  }
  __shared__ float r1[4], r2[4];
  if ((tid & 63) == 0) { r1[tid >> 6] = s1; r2[tid >> 6] = s2; }
  __syncthreads();
  s1 = r1[0] + r1[1] + r1[2] + r1[3];
  s2 = r2[0] + r2[1] + r2[2] + r2[3];
  float mu = s1 * (1.f / 1024.f);
  float var = s2 * (1.f / 1024.f) - mu * mu;
  float rs = rsqrtf(var + 1e-5f);
  float4 gv = *(const float4*)(g + tid * 4);
  float4 bv = *(const float4*)(bta + tid * 4);
  float4 o;
  o.x = (v.x - mu) * rs * gv.x + bv.x;
  o.y = (v.y - mu) * rs * gv.y + bv.y;
  o.z = (v.z - mu) * rs * gv.z + bv.z;
  o.w = (v.w - mu) * rs * gv.w + bv.w;
  *(float4*)(of + row * 1024 + tid * 4) = o;
  if (WB16) {
    ushort4 ov = make_ushort4(f2b(o.x), f2b(o.y), f2b(o.z), f2b(o.w));
    *(ushort4*)(ob + row * 1024 + tid * 4) = ov;
  }
}

extern "C" void kernel_launch(void* const* d_in, const int* in_sizes, int n_in,
                              void* d_out, int out_size, void* d_ws, size_t ws_size,
                              hipStream_t stream) {
  const float* x   = (const float*)d_in[0];
  const float* Wq  = (const float*)d_in[1];
  const float* bq  = (const float*)d_in[2];
  const float* Wk  = (const float*)d_in[3];
  const float* bk  = (const float*)d_in[4];
  const float* Wv  = (const float*)d_in[5];
  const float* bv  = (const float*)d_in[6];
  const float* Wo  = (const float*)d_in[7];
  const float* bo  = (const float*)d_in[8];
  const float* W1  = (const float*)d_in[9];
  const float* b1  = (const float*)d_in[10];
  const float* W2  = (const float*)d_in[11];
  const float* b2  = (const float*)d_in[12];
  const float* g1  = (const float*)d_in[13];
  const float* be1 = (const float*)d_in[14];
  const float* g2  = (const float*)d_in[15];
  const float* be2 = (const float*)d_in[16];

  float* out = (float*)d_out;
  float* attn = out + 4194304LL;  // [4,16,1024,1024] fp32

  char* w = (char*)d_ws;
  size_t off = 0;
  auto alloc = [&](size_t bytes) {
    void* p = w + off;
    off = (off + bytes + 255) & ~(size_t)255;
    return p;
  };
  u16* xb        = (u16*)alloc(8388608);    // x bf16 [4096,1024]
  u16* Wqkvt     = (u16*)alloc(6291456);    // [3072,1024] bf16 (Wq^T|Wk^T|Wv^T)
  u16* Wot       = (u16*)alloc(2097152);    // [1024,1024]
  u16* W1t       = (u16*)alloc(8388608);    // [4096,1024]
  u16* W2t       = (u16*)alloc(8388608);    // [1024,4096]
  float* bqkv    = (float*)alloc(12288);    // [3072]
  u16* qkvb      = (u16*)alloc(25165824);   // [4096,3072] bf16
  u16* vtb       = (u16*)alloc(8388608);    // [64,64,1024] bf16
  u16* ctxb      = (u16*)alloc(8388608);    // [4096,1024] bf16
  float* attn_o  = (float*)alloc(16777216); // [4096,1024] fp32
  float* x1      = (float*)alloc(16777216); // post-LN1 fp32
  u16* x1b       = (u16*)alloc(8388608);
  u16* ff1b      = (u16*)alloc(33554432);   // [4096,4096] bf16
  float* ff2     = (float*)alloc(16777216);
  (void)ws_size; (void)in_sizes; (void)n_in; (void)out_size;

  dim3 tb(32, 8);
  // pack inputs to bf16 / transposed-bf16
  cast_k<<<4096, 256, 0, stream>>>(x, xb, 1048576);
  transpose_k<<<dim3(32, 32), tb, 0, stream>>>(Wq, Wqkvt,           1024, 1024);
  transpose_k<<<dim3(32, 32), tb, 0, stream>>>(Wk, Wqkvt + 1048576, 1024, 1024);
  transpose_k<<<dim3(32, 32), tb, 0, stream>>>(Wv, Wqkvt + 2097152, 1024, 1024);
  transpose_k<<<dim3(32, 32), tb, 0, stream>>>(Wo, Wot, 1024, 1024);
  transpose_k<<<dim3(128, 32), tb, 0, stream>>>(W1, W1t, 4096, 1024);
  transpose_k<<<dim3(32, 128), tb, 0, stream>>>(W2, W2t, 1024, 4096);
  hipMemcpyAsync(bqkv,        bq, 4096, hipMemcpyDeviceToDevice, stream);
  hipMemcpyAsync(bqkv + 1024, bk, 4096, hipMemcpyDeviceToDevice, stream);
  hipMemcpyAsync(bqkv + 2048, bv, 4096, hipMemcpyDeviceToDevice, stream);

  // QKV projection: [4096,1024]x[1024,3072] -> qkvb bf16
  gemm_k<128, 0, 1, 0, 1, 0><<<dim3(24, 32, 1), 256, 0, stream>>>(
      xb, nullptr, 0, 0, 1024, Wqkvt, 0, 0, 1024,
      nullptr, qkvb, 0, 0, 3072, bqkv, 1024, 1);

  transpose_v_k<<<dim3(32, 2, 64), tb, 0, stream>>>(qkvb, vtb);

  // scores: per (b,h): Q[1024,64] x K^T -> attn region (pre-softmax, fp32)
  gemm_k<128, 0, 0, 0, 0, 1><<<dim3(8, 8, 64), 256, 0, stream>>>(
      qkvb, nullptr, 3145728, 64, 3072,
      qkvb + 1024, 3145728, 64, 3072,
      attn, nullptr, 16777216, 1048576, 1024, nullptr, 64, 16);

  softmax_k<<<65536, 256, 0, stream>>>(attn);

  // ctx: per (b,h): attn[1024,1024](fp32) x V[1024,64] -> ctxb bf16 [4096,1024]
  gemm_k<64, 1, 0, 0, 1, 0><<<dim3(1, 8, 64), 256, 0, stream>>>(
      nullptr, attn, 16777216, 1048576, 1024,
      vtb, 1048576, 65536, 1024,
      nullptr, ctxb, 1048576, 64, 1024, nullptr, 1024, 16);

  // attn_out = ctx x Wo + bo (fp32)
  gemm_k<128, 0, 1, 0, 0, 1><<<dim3(8, 32, 1), 256, 0, stream>>>(
      ctxb, nullptr, 0, 0, 1024, Wot, 0, 0, 1024,
      attn_o, nullptr, 0, 0, 1024, bo, 1024, 1);

  // x1 = LN(x + attn_out)
  add_ln_k<1><<<4096, 256, 0, stream>>>(x, attn_o, g1, be1, x1, x1b);

  // ff1 = relu(x1 W1 + b1) -> bf16
  gemm_k<128, 0, 1, 1, 1, 0><<<dim3(32, 32, 1), 256, 0, stream>>>(
      x1b, nullptr, 0, 0, 1024, W1t, 0, 0, 1024,
      nullptr, ff1b, 0, 0, 4096, b1, 1024, 1);

  // ff2 = ff1 W2 + b2 (fp32)
  gemm_k<128, 0, 1, 0, 0, 1><<<dim3(8, 32, 1), 256, 0, stream>>>(
      ff1b, nullptr, 0, 0, 4096, W2t, 0, 0, 4096,
      ff2, nullptr, 0, 0, 1024, b2, 4096, 1);

  // out = LN(x1 + ff2)
  add_ln_k<0><<<4096, 256, 0, stream>>>(x1, ff2, g2, be2, out, nullptr);
}